// Round 12
// baseline (70.592 us; speedup 1.0000x reference)
//
#include <hip/hip_runtime.h>

#define IN_CH 64
#define OUT_CH 128
#define HW 128
#define KTAPS 9
#define ROWB 16384             // bytes per staged row image: 128 w * 64 ic * 2B
#define ATAP 16384             // bytes per tap A-tile: 128 oc * 64 ic * 2B

typedef __bf16 bf16x8 __attribute__((ext_vector_type(8)));
typedef float f32x16 __attribute__((ext_vector_type(16)));
typedef float f32x4 __attribute__((ext_vector_type(4)));

// fp32 -> bf16 round-to-nearest-even (data has no NaN/Inf) — prep use
__device__ __forceinline__ unsigned f2bf(float f) {
    unsigned u = __builtin_bit_cast(unsigned, f);
    return (u + 0x7FFFu + ((u >> 16) & 1u)) >> 16;
}

// HW packed f32x2 -> bf16x2 (RNE), 1 instruction (no builtin on gfx950)
__device__ __forceinline__ unsigned cvt_pk_bf16(float lo, float hi) {
    unsigned r;
    asm("v_cvt_pk_bf16_f32 %0, %1, %2" : "=v"(r) : "v"(lo), "v"(hi));
    return r;   // [15:0]=bf16(lo), [31:16]=bf16(hi)
}

// 16B-granule XOR swizzle keyed by row (B-tile only; A needs none — see wprep).
__device__ __forceinline__ int swz(int r) { return ((r ^ (r >> 3)) & 7) << 4; }

__device__ __forceinline__ void gload_lds16(const void* g, void* l) {
    __builtin_amdgcn_global_load_lds(
        (const __attribute__((address_space(1))) unsigned int*)g,
        (__attribute__((address_space(3))) unsigned int*)l, 16, 0, 0);
}

// W (OIHW fp32) -> Wl: 9 tap-tiles of 16KB, fragment-ordered LINEAR so the
// tile DMAs straight into LDS and each wave's A-reads are 4 lane-contiguous
// ds_read_b128 (conflict-free, no swizzle):
//   16B chunk c = (pm*4 + ks)*64 + lane   (pm = wave oc-quarter 0..3)
//   chunk holds 8 bf16 of A[oc = pm*32+(lane&31)][ic = ks*16+(lane>>5)*8 ..+8]
__global__ void wprep_kernel(const float* __restrict__ W, unsigned short* __restrict__ Wl) {
    int i = blockIdx.x * blockDim.x + threadIdx.x;   // 73728 bf16 elements
    if (i >= OUT_CH * IN_CH * KTAPS) return;
    int t  = i >> 13;          // tap 0..8 (8192 elems per tap)
    int r  = i & 8191;
    int c  = r >> 3;           // chunk 0..1023
    int e  = r & 7;
    int l  = c & 63;
    int q2 = c >> 6;           // (pm*4 + ks)
    int ks = q2 & 3;
    int pm = q2 >> 2;
    int oc = pm * 32 + (l & 31);
    int ic = ks * 16 + (l >> 5) * 8 + e;
    int kh = t / 3, kw = t % 3;
    Wl[i] = (unsigned short)f2bf(W[((oc * IN_CH + ic) * 3 + kh) * 3 + kw]);
}

// Fused conv: 512 threads / 8 thin waves (32oc x 64w, acc=32) per (n,h);
// B staged once (cvt_pk, balanced, swizzled); A tap-tiles ping-pong through
// LDS via global_load_lds DMA (latency carried by the DMA engine, drained at
// the per-tap barrier under the tap's own compute + the co-resident block).
// LDS 80KB -> 2 blocks/CU = 4 waves/SIMD.
__global__ __launch_bounds__(512, 4) void conv_kernel_f(
    const float* __restrict__ x, const unsigned short* __restrict__ Wl,
    const float* __restrict__ bias, float* __restrict__ y)
{
    __shared__ __align__(16) unsigned char xsB[3 * ROWB];   // 48 KiB
    __shared__ __align__(16) unsigned char xsA[2 * ATAP];   // 32 KiB

    int bid = blockIdx.x;
    int sb  = (bid & 7) * 256 + (bid >> 3);   // XCD-contiguous h ranges (bijective: 2048 = 8*256)
    int n = sb >> 7, h = sb & 127;
    int tid = threadIdx.x;
    int wid = tid >> 6, lane = tid & 63;

    // ---- prologue: tap-0 A DMA first (flies under all of B staging) ----
    {
        const unsigned char* asrc = (const unsigned char*)Wl;   // tap 0
        #pragma unroll
        for (int j = 0; j < 2; ++j) {
            int off = wid * 2048 + j * 1024;   // wave-uniform LDS base
            gload_lds16(asrc + off + lane * 16, xsA + off);
        }
    }

    // ---- stage 3 B-rows (h-8, h, h+8): 1536 quarter-groups (kh, ic4, w4),
    //      exactly 3 per thread; 4 float4 loads -> 8 cvt_pk -> 4 b64 writes.
    #pragma unroll
    for (int g = 0; g < 3; ++g) {
        int q   = g * 512 + tid;     // 0..1535
        int w4  = q & 31;
        int ic4 = (q >> 5) & 15;
        int kh  = q >> 9;
        int srow = (h + kh * 8 + 120) & 127;   // h-8, h, h+8 (mod 128)
        const float* xp = x + (((n * IN_CH + ic4 * 4) * HW + srow) * HW + w4 * 4);
        f32x4 v[4];
        #pragma unroll
        for (int j = 0; j < 4; ++j)
            v[j] = *reinterpret_cast<const f32x4*>(xp + j * (HW * HW));
        #pragma unroll
        for (int j2 = 0; j2 < 4; ++j2) {
            int w = w4 * 4 + j2;
            uint2 pk;
            pk.x = cvt_pk_bf16(v[0][j2], v[1][j2]);
            pk.y = cvt_pk_bf16(v[2][j2], v[3][j2]);
            *reinterpret_cast<uint2*>(xsB + kh * ROWB + ((w * 128 + ic4 * 8) ^ swz(w))) = pk;
        }
    }
    __syncthreads();   // drains staging writes AND the tap-0 DMA

    // wave roles: wr = oc quarter (32 rows), wc = w half (64 cols)
    int wr = wid >> 1, wc = wid & 1;
    int l31 = lane & 31, lhi = lane >> 5;

    f32x16 acc[2];
    #pragma unroll
    for (int bq = 0; bq < 2; ++bq)
        #pragma unroll
        for (int r = 0; r < 16; ++r) acc[bq][r] = 0.0f;

    #pragma unroll
    for (int t = 0; t < 9; ++t) {
        // phase 1: DMA next tap's A-tile into the other buffer
        if (t < 8) {
            const unsigned char* asrc = (const unsigned char*)Wl + (t + 1) * ATAP;
            unsigned char* adst = xsA + ((t + 1) & 1) * ATAP;
            #pragma unroll
            for (int j = 0; j < 2; ++j) {
                int off = wid * 2048 + j * 1024;
                gload_lds16(asrc + off + lane * 16, adst + off);
            }
        }
        // phase 2: ds_read A-frags (lane-contiguous, conflict-free) + B + MFMA
        const unsigned char* At = xsA + (t & 1) * ATAP + wr * 4096;
        int kh = t / 3, kw = t % 3;
        int xc0 = (wc * 64 + l31 + 8 * kw - 8) & 127;   // circular column
        int xc1 = (xc0 + 32) & 127;
        int b0base = kh * ROWB + xc0 * 128 + lhi * 16, s0 = swz(xc0);
        int b1base = kh * ROWB + xc1 * 128 + lhi * 16, s1 = swz(xc1);
        #pragma unroll
        for (int ks = 0; ks < 4; ++ks) {   // K=16 per MFMA, 64 ic per tap
            bf16x8 a  = *reinterpret_cast<const bf16x8*>(At + ks * 1024 + lane * 16);
            bf16x8 b0 = *reinterpret_cast<const bf16x8*>(xsB + ((b0base + ks * 32) ^ s0));
            bf16x8 b1 = *reinterpret_cast<const bf16x8*>(xsB + ((b1base + ks * 32) ^ s1));
            acc[0] = __builtin_amdgcn_mfma_f32_32x32x16_bf16(a, b0, acc[0], 0, 0, 0);
            acc[1] = __builtin_amdgcn_mfma_f32_32x32x16_bf16(a, b1, acc[1], 0, 0, 0);
        }
        // barrier: waves done with buf[t&1] before tap t+1 DMAs over it at t+2;
        // drain of the just-issued DMA hides under this tap's ds_reads+MFMAs.
        if (t < 8) __syncthreads();
    }

    // ---- epilogue: bias + store. D: col=l31(w), row=(reg&3)+8*(reg>>2)+4*lhi ----
    int outbase = (n * OUT_CH) * HW * HW + h * HW;
    #pragma unroll
    for (int bq = 0; bq < 2; ++bq) {
        int wcol = wc * 64 + bq * 32 + l31;
        #pragma unroll
        for (int reg = 0; reg < 16; ++reg) {
            int oc = wr * 32 + (reg & 3) + 8 * (reg >> 2) + 4 * lhi;
            y[outbase + oc * HW * HW + wcol] = acc[bq][reg] + bias[oc];
        }
    }
}

extern "C" void kernel_launch(void* const* d_in, const int* in_sizes, int n_in,
                              void* d_out, int out_size, void* d_ws, size_t ws_size,
                              hipStream_t stream) {
    const float* x = (const float*)d_in[0];
    const float* W = (const float*)d_in[1];
    const float* b = (const float*)d_in[2];
    float* y = (float*)d_out;

    unsigned short* Wl = (unsigned short*)d_ws;   // 147456 B

    hipLaunchKernelGGL(wprep_kernel, dim3((OUT_CH * IN_CH * KTAPS + 255) / 256), dim3(256), 0, stream, W, Wl);
    hipLaunchKernelGGL(conv_kernel_f, dim3(16 * HW), dim3(512), 0, stream, x, Wl, b, y);
}

// Round 13
// 68.918 us; speedup vs baseline: 1.0243x; 1.0243x over previous
//
#include <hip/hip_runtime.h>

#define IN_CH 64
#define OUT_CH 128
#define HW 128
#define KTAPS 9
#define ROWB 16384             // bytes per staged row image: 128 w * 64 ic * 2B

typedef __bf16 bf16x8 __attribute__((ext_vector_type(8)));
typedef float f32x16 __attribute__((ext_vector_type(16)));
typedef float f32x4 __attribute__((ext_vector_type(4)));

// fp32 -> bf16 round-to-nearest-even (data has no NaN/Inf) — prep use
__device__ __forceinline__ unsigned f2bf(float f) {
    unsigned u = __builtin_bit_cast(unsigned, f);
    return (u + 0x7FFFu + ((u >> 16) & 1u)) >> 16;
}

// HW packed f32x2 -> bf16x2 (RNE), 1 instruction (no builtin on gfx950)
__device__ __forceinline__ unsigned cvt_pk_bf16(float lo, float hi) {
    unsigned r;
    asm("v_cvt_pk_bf16_f32 %0, %1, %2" : "=v"(r) : "v"(lo), "v"(hi));
    return r;   // [15:0]=bf16(lo), [31:16]=bf16(hi)
}

// 16B-granule XOR swizzle keyed by row (3 bits -> byte-addr bits 4..6).
__device__ __forceinline__ int swz(int r) { return ((r ^ (r >> 3)) & 7) << 4; }

// W (OIHW fp32) -> Wl in wave-fragment order (PROVEN R9-R11):
// 16B chunk index = (p*9 + t)*512 + (m*4 + ks)*64 + lane
// Chunk content: 8 bf16 of A[oc = p*64+m*32+(lane&31)][ic = ks*16+(lane>>5)*8 ..+8].
__global__ void wprep_kernel(const float* __restrict__ W, unsigned short* __restrict__ Wl) {
    int i = blockIdx.x * blockDim.x + threadIdx.x;   // 73728 bf16 elements
    if (i >= OUT_CH * IN_CH * KTAPS) return;
    int p  = i / 36864;
    int r  = i % 36864;
    int t  = r >> 12;          // 0..8
    int r2 = r & 4095;
    int m  = r2 >> 11;
    int ks = (r2 >> 9) & 3;
    int l  = (r2 >> 3) & 63;
    int e  = r2 & 7;
    int oc = p * 64 + m * 32 + (l & 31);
    int ic = ks * 16 + (l >> 5) * 8 + e;
    int kh = t / 3, kw = t % 3;
    Wl[i] = (unsigned short)f2bf(W[((oc * IN_CH + ic) * 3 + kh) * 3 + kw]);
}

// h-paired fused conv: one 512-thread block computes outputs (n,h0) AND
// (n,h0+8), staging the 4 shared input rows (h0-8, h0, h0+8, h0+16) once.
// 8 waves = {hq} x {oc-pair wp} x {wc}; each wave computes TWO 32oc x 64w
// quarter-tiles sharing its B-reads (B LDS traffic per output halved).
// Single barrier; A loads compiler-scheduled from L2-resident Wl.
__global__ __launch_bounds__(512, 3) void conv_kernel_f(
    const float* __restrict__ x, const unsigned short* __restrict__ Wl,
    const float* __restrict__ bias, float* __restrict__ y)
{
    __shared__ __align__(16) unsigned char xsB[4 * ROWB];   // 64 KiB -> 2 blocks/CU

    int bid = blockIdx.x;                      // 1024 blocks
    int sb  = (bid & 7) * 128 + (bid >> 3);    // XCD swizzle (bijective: 1024 = 8*128)
    int n   = sb >> 6;
    int pp  = sb & 63;
    int h0  = (pp >> 3) * 16 + (pp & 7);       // outputs (h0, h0+8), covers all h
    int tid = threadIdx.x;
    int wid = tid >> 6, lane = tid & 63;

    // ---- stage 4 rows (h0-8, h0, h0+8, h0+16): 2048 quarter-groups
    //      (r, ic4, w4), exactly 4/thread; 4 float4 -> 8 cvt_pk -> 4 b64 each.
    #pragma unroll
    for (int g = 0; g < 4; ++g) {
        int q   = g * 512 + tid;     // 0..2047
        int w4  = q & 31;
        int ic4 = (q >> 5) & 15;
        int r   = q >> 9;            // 0..3
        int srow = (h0 + r * 8 + 120) & 127;   // h0-8 + 8r (mod 128)
        const float* xp = x + (((n * IN_CH + ic4 * 4) * HW + srow) * HW + w4 * 4);
        f32x4 v[4];
        #pragma unroll
        for (int j = 0; j < 4; ++j)
            v[j] = *reinterpret_cast<const f32x4*>(xp + j * (HW * HW));
        #pragma unroll
        for (int j2 = 0; j2 < 4; ++j2) {
            int w = w4 * 4 + j2;
            uint2 pk;
            pk.x = cvt_pk_bf16(v[0][j2], v[1][j2]);
            pk.y = cvt_pk_bf16(v[2][j2], v[3][j2]);
            *reinterpret_cast<uint2*>(xsB + r * ROWB + ((w * 128 + ic4 * 8) ^ swz(w))) = pk;
        }
    }
    __syncthreads();   // the ONLY barrier

    // wave roles: hq = output row (h0 / h0+8), wp = oc-pair, wc = w half
    int hq = wid >> 2;
    int wp = (wid >> 1) & 1;
    int wc = wid & 1;
    int l31 = lane & 31, lhi = lane >> 5;

    // Two A-frag streams: quarters pm = wp (p=0,m=wp) and pm = 2+wp (p=1,m=wp)
    const bf16x8* Ab0 = reinterpret_cast<const bf16x8*>(Wl) + 0 * (9 * 512) + wp * 256 + lane;
    const bf16x8* Ab1 = reinterpret_cast<const bf16x8*>(Wl) + 1 * (9 * 512) + wp * 256 + lane;

    f32x16 acc[2][2];   // [quarter-set][bq] — all indices compile-time after unroll
    #pragma unroll
    for (int qs = 0; qs < 2; ++qs)
        #pragma unroll
        for (int bq = 0; bq < 2; ++bq)
            #pragma unroll
            for (int r = 0; r < 16; ++r) acc[qs][bq][r] = 0.0f;

    #pragma unroll
    for (int t = 0; t < 9; ++t) {
        // per-tap A fragments for both quarters (8 lane-contiguous 1KB loads, L2)
        bf16x8 a0[4], a1[4];
        #pragma unroll
        for (int ks = 0; ks < 4; ++ks) {
            a0[ks] = Ab0[t * 512 + ks * 64];
            a1[ks] = Ab1[t * 512 + ks * 64];
        }
        int kh = t / 3, kw = t % 3;
        int br  = (kh + hq) * ROWB;                      // staged row for this tap/output
        int xc0 = (wc * 64 + l31 + 8 * kw - 8) & 127;    // circular column
        int xc1 = (xc0 + 32) & 127;
        int b0base = br + xc0 * 128 + lhi * 16, s0 = swz(xc0);
        int b1base = br + xc1 * 128 + lhi * 16, s1 = swz(xc1);
        #pragma unroll
        for (int ks = 0; ks < 4; ++ks) {   // K=16 per MFMA; each B frag feeds 4 MFMAs
            bf16x8 b0 = *reinterpret_cast<const bf16x8*>(xsB + ((b0base + ks * 32) ^ s0));
            bf16x8 b1 = *reinterpret_cast<const bf16x8*>(xsB + ((b1base + ks * 32) ^ s1));
            acc[0][0] = __builtin_amdgcn_mfma_f32_32x32x16_bf16(a0[ks], b0, acc[0][0], 0, 0, 0);
            acc[0][1] = __builtin_amdgcn_mfma_f32_32x32x16_bf16(a0[ks], b1, acc[0][1], 0, 0, 0);
            acc[1][0] = __builtin_amdgcn_mfma_f32_32x32x16_bf16(a1[ks], b0, acc[1][0], 0, 0, 0);
            acc[1][1] = __builtin_amdgcn_mfma_f32_32x32x16_bf16(a1[ks], b1, acc[1][1], 0, 0, 0);
        }
    }

    // ---- epilogue: bias + store. D: col=l31(w), row=(reg&3)+8*(reg>>2)+4*lhi ----
    int hout = h0 + hq * 8;
    int outbase = (n * OUT_CH) * HW * HW + hout * HW;
    #pragma unroll
    for (int qs = 0; qs < 2; ++qs) {
        int ocb = qs * 64 + wp * 32;     // quarter pm = qs*2 + wp -> oc base
        #pragma unroll
        for (int bq = 0; bq < 2; ++bq) {
            int wcol = wc * 64 + bq * 32 + l31;
            #pragma unroll
            for (int reg = 0; reg < 16; ++reg) {
                int oc = ocb + (reg & 3) + 8 * (reg >> 2) + 4 * lhi;
                y[outbase + oc * HW * HW + wcol] = acc[qs][bq][reg] + bias[oc];
            }
        }
    }
}

extern "C" void kernel_launch(void* const* d_in, const int* in_sizes, int n_in,
                              void* d_out, int out_size, void* d_ws, size_t ws_size,
                              hipStream_t stream) {
    const float* x = (const float*)d_in[0];
    const float* W = (const float*)d_in[1];
    const float* b = (const float*)d_in[2];
    float* y = (float*)d_out;

    unsigned short* Wl = (unsigned short*)d_ws;   // 147456 B

    hipLaunchKernelGGL(wprep_kernel, dim3((OUT_CH * IN_CH * KTAPS + 255) / 256), dim3(256), 0, stream, W, Wl);
    hipLaunchKernelGGL(conv_kernel_f, dim3(1024), dim3(512), 0, stream, x, Wl, b, y);
}

// Round 14
// 61.221 us; speedup vs baseline: 1.1531x; 1.1257x over previous
//
#include <hip/hip_runtime.h>

#define IN_CH 64
#define OUT_CH 128
#define HW 128
#define KTAPS 9
#define ROWB 16384             // bytes per staged row image: 128 w * 64 ic * 2B

typedef __bf16 bf16x8 __attribute__((ext_vector_type(8)));
typedef float f32x16 __attribute__((ext_vector_type(16)));
typedef float f32x4 __attribute__((ext_vector_type(4)));

// fp32 -> bf16 round-to-nearest-even (data has no NaN/Inf) — prep use
__device__ __forceinline__ unsigned f2bf(float f) {
    unsigned u = __builtin_bit_cast(unsigned, f);
    return (u + 0x7FFFu + ((u >> 16) & 1u)) >> 16;
}

// HW packed f32x2 -> bf16x2 (RNE), 1 instruction (no builtin on gfx950)
__device__ __forceinline__ unsigned cvt_pk_bf16(float lo, float hi) {
    unsigned r;
    asm("v_cvt_pk_bf16_f32 %0, %1, %2" : "=v"(r) : "v"(lo), "v"(hi));
    return r;   // [15:0]=bf16(lo), [31:16]=bf16(hi)
}

// 16B-granule XOR swizzle keyed by row (3 bits -> byte-addr bits 4..6).
__device__ __forceinline__ int swz(int r) { return ((r ^ (r >> 3)) & 7) << 4; }

// W (OIHW fp32) -> Wl in wave-fragment order (PROVEN R9-R13):
// 16B chunk index = (p*9 + t)*512 + (m*4 + ks)*64 + lane
// Chunk content: 8 bf16 of A[oc = p*64+m*32+(lane&31)][ic = ks*16+(lane>>5)*8 ..+8].
__global__ void wprep_kernel(const float* __restrict__ W, unsigned short* __restrict__ Wl) {
    int i = blockIdx.x * blockDim.x + threadIdx.x;   // 73728 bf16 elements
    if (i >= OUT_CH * IN_CH * KTAPS) return;
    int p  = i / 36864;
    int r  = i % 36864;
    int t  = r >> 12;          // 0..8
    int r2 = r & 4095;
    int m  = r2 >> 11;
    int ks = (r2 >> 9) & 3;
    int l  = (r2 >> 3) & 63;
    int e  = r2 & 7;
    int oc = p * 64 + m * 32 + (l & 31);
    int ic = ks * 16 + (l >> 5) * 8 + e;
    int kh = t / 3, kw = t % 3;
    Wl[i] = (unsigned short)f2bf(W[((oc * IN_CH + ic) * 3 + kh) * 3 + kw]);
}

// Issue one tap's 4 A-fragment loads as volatile asm (compiler cannot sink
// them to their consumers — the R7/R11 failure). Base is per-lane; taps are
// reached with immediate offsets (13-bit signed, max 3072 here).
#define ISSUE_A(B0, B1, B2, B3, T) do {                                              \
    const char* _pp = (const char*)Ab + (T) * 8192;                                  \
    asm volatile("global_load_dwordx4 %0, %1, off"             : "=v"(B0) : "v"(_pp)); \
    asm volatile("global_load_dwordx4 %0, %1, off offset:1024" : "=v"(B1) : "v"(_pp)); \
    asm volatile("global_load_dwordx4 %0, %1, off offset:2048" : "=v"(B2) : "v"(_pp)); \
    asm volatile("global_load_dwordx4 %0, %1, off offset:3072" : "=v"(B3) : "v"(_pp)); \
} while (0)

// One tap's compute: counted vmcnt wait (never 0 until the last tap) +
// sched_barrier(0) fence (rule #18), then 8 swizzled ds_read_b128 + 8 MFMAs.
#define TAP_BODY(A0_, A1_, A2_, A3_, T, WAITSTR) do {                                \
    constexpr int _kh = (T) / 3, _kw = (T) % 3;                                      \
    int _xc0 = (wc * 64 + l31 + 8 * _kw - 8) & 127;                                  \
    int _xc1 = (_xc0 + 32) & 127;                                                    \
    int _b0 = _kh * ROWB + _xc0 * 128 + lhi * 16, _s0 = swz(_xc0);                   \
    int _b1 = _kh * ROWB + _xc1 * 128 + lhi * 16, _s1 = swz(_xc1);                   \
    asm volatile(WAITSTR);                                                           \
    __builtin_amdgcn_sched_barrier(0);                                               \
    const bf16x8 _A[4] = {A0_, A1_, A2_, A3_};                                       \
    _Pragma("unroll")                                                                \
    for (int ks = 0; ks < 4; ++ks) {                                                 \
        bf16x8 _vb0 = *reinterpret_cast<const bf16x8*>(xsB + ((_b0 + ks * 32) ^ _s0)); \
        bf16x8 _vb1 = *reinterpret_cast<const bf16x8*>(xsB + ((_b1 + ks * 32) ^ _s1)); \
        acc[0] = __builtin_amdgcn_mfma_f32_32x32x16_bf16(_A[ks], _vb0, acc[0], 0, 0, 0); \
        acc[1] = __builtin_amdgcn_mfma_f32_32x32x16_bf16(_A[ks], _vb1, acc[1], 0, 0, 0); \
    }                                                                                \
} while (0)

// Fused conv (R11 skeleton): 512 threads / 8 thin waves (32oc x 64w, acc=32)
// per (n,h); B staged once (cvt_pk, balanced, swizzled); A streamed from
// L2-resident Wl through an asm counted-vmcnt double-buffer pipeline.
__global__ __launch_bounds__(512, 5) void conv_kernel_f(
    const float* __restrict__ x, const unsigned short* __restrict__ Wl,
    const float* __restrict__ bias, float* __restrict__ y)
{
    __shared__ __align__(16) unsigned char xsB[3 * ROWB];   // 48 KiB -> 3 blocks/CU

    int bid = blockIdx.x;
    int sb  = (bid & 7) * 256 + (bid >> 3);   // XCD-contiguous h ranges (bijective: 2048 = 8*256)
    int n = sb >> 7, h = sb & 127;
    int tid = threadIdx.x;
    int wid = tid >> 6, lane = tid & 63;

    // wave roles: wr = oc quarter (32 rows), wc = w half (64 cols)
    int wr = wid >> 1, wc = wid & 1;
    int l31 = lane & 31, lhi = lane >> 5;
    int p = wr >> 1, m = wr & 1;

    // A chunk pointer (16B units): proven fragment order, quarter-selected.
    const bf16x8* Ab = reinterpret_cast<const bf16x8*>(Wl)
                     + p * (9 * 512) + m * 256 + lane;

    // tap-0 A loads issued FIRST (asm, cannot sink): fly under all of staging;
    // the staging barrier's vmcnt(0) drain guarantees they're ready for tap 0.
    bf16x8 aE0, aE1, aE2, aE3, aO0, aO1, aO2, aO3;
    ISSUE_A(aE0, aE1, aE2, aE3, 0);

    // ---- stage 3 B-rows (h-8, h, h+8): 1536 quarter-groups (kh, ic4, w4),
    //      exactly 3 per thread; 4 float4 loads -> 8 cvt_pk -> 4 b64 writes.
    #pragma unroll
    for (int g = 0; g < 3; ++g) {
        int q   = g * 512 + tid;     // 0..1535
        int w4  = q & 31;
        int ic4 = (q >> 5) & 15;
        int kh  = q >> 9;
        int srow = (h + kh * 8 + 120) & 127;   // h-8, h, h+8 (mod 128)
        const float* xp = x + (((n * IN_CH + ic4 * 4) * HW + srow) * HW + w4 * 4);
        f32x4 v[4];
        #pragma unroll
        for (int j = 0; j < 4; ++j)
            v[j] = *reinterpret_cast<const f32x4*>(xp + j * (HW * HW));
        #pragma unroll
        for (int j2 = 0; j2 < 4; ++j2) {
            int w = w4 * 4 + j2;
            uint2 pk;
            pk.x = cvt_pk_bf16(v[0][j2], v[1][j2]);
            pk.y = cvt_pk_bf16(v[2][j2], v[3][j2]);
            *reinterpret_cast<uint2*>(xsB + kh * ROWB + ((w * 128 + ic4 * 8) ^ swz(w))) = pk;
        }
    }
    __syncthreads();   // the ONLY barrier (drains staging + tap-0 A loads)

    f32x16 acc[2];
    #pragma unroll
    for (int bq = 0; bq < 2; ++bq)
        #pragma unroll
        for (int r = 0; r < 16; ++r) acc[bq][r] = 0.0f;

    // ---- K-loop: asm double-buffered A, counted vmcnt(4), one-tap lookahead.
    // Steady state keeps 4-8 loads in flight; never drains to 0 until t=8.
    ISSUE_A(aO0, aO1, aO2, aO3, 1);
    TAP_BODY(aE0, aE1, aE2, aE3, 0, "s_waitcnt vmcnt(4)");
    ISSUE_A(aE0, aE1, aE2, aE3, 2);
    TAP_BODY(aO0, aO1, aO2, aO3, 1, "s_waitcnt vmcnt(4)");
    ISSUE_A(aO0, aO1, aO2, aO3, 3);
    TAP_BODY(aE0, aE1, aE2, aE3, 2, "s_waitcnt vmcnt(4)");
    ISSUE_A(aE0, aE1, aE2, aE3, 4);
    TAP_BODY(aO0, aO1, aO2, aO3, 3, "s_waitcnt vmcnt(4)");
    ISSUE_A(aO0, aO1, aO2, aO3, 5);
    TAP_BODY(aE0, aE1, aE2, aE3, 4, "s_waitcnt vmcnt(4)");
    ISSUE_A(aE0, aE1, aE2, aE3, 6);
    TAP_BODY(aO0, aO1, aO2, aO3, 5, "s_waitcnt vmcnt(4)");
    ISSUE_A(aO0, aO1, aO2, aO3, 7);
    TAP_BODY(aE0, aE1, aE2, aE3, 6, "s_waitcnt vmcnt(4)");
    ISSUE_A(aE0, aE1, aE2, aE3, 8);
    TAP_BODY(aO0, aO1, aO2, aO3, 7, "s_waitcnt vmcnt(4)");
    TAP_BODY(aE0, aE1, aE2, aE3, 8, "s_waitcnt vmcnt(0)");

    // ---- epilogue: bias + store. D: col=l31(w), row=(reg&3)+8*(reg>>2)+4*lhi ----
    int outbase = (n * OUT_CH) * HW * HW + h * HW;
    #pragma unroll
    for (int bq = 0; bq < 2; ++bq) {
        int wcol = wc * 64 + bq * 32 + l31;
        #pragma unroll
        for (int reg = 0; reg < 16; ++reg) {
            int oc = wr * 32 + (reg & 3) + 8 * (reg >> 2) + 4 * lhi;
            y[outbase + oc * HW * HW + wcol] = acc[bq][reg] + bias[oc];
        }
    }
}

extern "C" void kernel_launch(void* const* d_in, const int* in_sizes, int n_in,
                              void* d_out, int out_size, void* d_ws, size_t ws_size,
                              hipStream_t stream) {
    const float* x = (const float*)d_in[0];
    const float* W = (const float*)d_in[1];
    const float* b = (const float*)d_in[2];
    float* y = (float*)d_out;

    unsigned short* Wl = (unsigned short*)d_ws;   // 147456 B

    hipLaunchKernelGGL(wprep_kernel, dim3((OUT_CH * IN_CH * KTAPS + 255) / 256), dim3(256), 0, stream, W, Wl);
    hipLaunchKernelGGL(conv_kernel_f, dim3(16 * HW), dim3(512), 0, stream, x, Wl, b, y);
}